// Round 3
// baseline (215.597 us; speedup 1.0000x reference)
//
#include <hip/hip_runtime.h>
#include <hip/hip_bf16.h>

// TAttention: B=16, C=32, N=1024, T=128, R=10
// Fast path (needs ~140 MB ws):
//   K1 fused: k(regs) + x->bf16 (pre-swizzled) + kw partials   [x read 1x]
//   K2: scores + softmax -> att bf16
//   K3: persistent out_gemm, att staged once, x dbuf pipeline   [x_bf16 read]
// Traffic ~816 MB -> ~117 us floor @ 7 TB/s.

#define B_ 16
#define C_ 32
#define N_ 1024
#define T_ 128
#define R_ 10
#define CH_ 16          // legacy path chunks
#define NCH_ (N_ / CH_)

typedef __bf16 bf16x8 __attribute__((ext_vector_type(8)));
typedef __bf16 bf16x4 __attribute__((ext_vector_type(4)));
typedef float f32x4 __attribute__((ext_vector_type(4)));
typedef float f32x2 __attribute__((ext_vector_type(2)));

// ================================================================ FAST PATH
// ---------------------------------------------------------------- kernel 1
// block = (b, nc of 64 n, c-half of 16): stream x contiguously, acc k in regs,
// write x_bf16 pre-swizzled (byte ^= (row&7)<<4 within 256B rows), then kw
// partials via LDS. p1/p2: [b][32ch][t][r].
__global__ __launch_bounds__(256) void k_cast_kw(const float* __restrict__ x,
                                                 const float* __restrict__ W1,
                                                 const float* __restrict__ W2,
                                                 const float* __restrict__ alpha,
                                                 __bf16* __restrict__ xb16,
                                                 float* __restrict__ p1,
                                                 float* __restrict__ p2) {
    __shared__ float klds[64][T_];               // 32 KB
    __shared__ __align__(16) float wl[64][24];   // W1 cols 0..9, W2 cols 12..21
    int bid = blockIdx.x;                        // ((b*16+nc)*2+h)
    int h   = bid & 1;
    int nc  = (bid >> 1) & 15;
    int b   = bid >> 5;
    int n0  = nc * 64, c0 = h * 16;
    int tid = threadIdx.x;

    for (int i = tid; i < 64 * 20; i += 256) {
        int nl = i & 63, q = i >> 6;
        wl[nl][q < 10 ? q : q + 2] =
            (q < 10) ? W1[q * N_ + n0 + nl] : W2[(q - 10) * N_ + n0 + nl];
    }
    float al[16];
    #pragma unroll
    for (int c = 0; c < 16; ++c) al[c] = alpha[c0 + c];

    int col = tid & 31;                          // float4 col (4 t each)
    f32x4 acc[8] = {};
    const float* xbase = x + (((size_t)b * C_ + c0) * N_ + n0) * T_;
    #pragma unroll 2
    for (int cc = 0; cc < 16; ++cc) {
        const float4* gx = reinterpret_cast<const float4*>(xbase + (size_t)cc * N_ * T_);
        char* xw = (char*)xb16 + (((size_t)(b * C_ + c0 + cc) * 16 + nc) * 16384);
        #pragma unroll
        for (int j = 0; j < 8; ++j) {
            float4 v = gx[tid + j * 256];
            int row = (tid >> 5) + j * 8;
            float a = al[cc];
            acc[j][0] += a * v.x; acc[j][1] += a * v.y;
            acc[j][2] += a * v.z; acc[j][3] += a * v.w;
            bf16x4 hv = {(__bf16)v.x, (__bf16)v.y, (__bf16)v.z, (__bf16)v.w};
            *reinterpret_cast<bf16x4*>(xw + row * 256 + ((col * 8) ^ ((row & 7) << 4))) = hv;
        }
    }
    #pragma unroll
    for (int j = 0; j < 8; ++j) {
        int row = (tid >> 5) + j * 8;
        *reinterpret_cast<f32x4*>(&klds[row][col * 4]) = acc[j];
    }
    __syncthreads();
    // kw partials: thread = (t, rg); rg=0 -> W1/p1, rg=1 -> W2/p2
    int t = tid & 127, rg = tid >> 7;
    float a[10] = {};
    #pragma unroll 4
    for (int n = 0; n < 64; ++n) {
        float kv = klds[n][t];
        const float* wr = &wl[n][rg * 12];
        f32x4 wA = *reinterpret_cast<const f32x4*>(wr);
        f32x4 wB = *reinterpret_cast<const f32x4*>(wr + 4);
        f32x2 wC = *reinterpret_cast<const f32x2*>(wr + 8);
        a[0] += kv * wA[0]; a[1] += kv * wA[1]; a[2] += kv * wA[2]; a[3] += kv * wA[3];
        a[4] += kv * wB[0]; a[5] += kv * wB[1]; a[6] += kv * wB[2]; a[7] += kv * wB[3];
        a[8] += kv * wC[0]; a[9] += kv * wC[1];
    }
    float* pd = (rg ? p2 : p1) + (((size_t)b * 32 + (bid & 31)) * T_ + t) * R_;
    #pragma unroll
    for (int q = 0; q < 5; ++q) {
        f32x2 v = {a[2 * q], a[2 * q + 1]};
        *reinterpret_cast<f32x2*>(pd + 2 * q) = v;
    }
}

// ---------------------------------------------------------------- kernel 2
__global__ __launch_bounds__(128) void scores_softmax32(const float* __restrict__ p1,
                                                        const float* __restrict__ p2,
                                                        __bf16* __restrict__ att) {
    __shared__ __align__(16) float kw1s[T_][12];
    __shared__ __align__(16) float kw2s[T_][12];
    __shared__ float sc[T_][T_ + 1];
    int b = blockIdx.x;
    int t = threadIdx.x;
    #pragma unroll
    for (int r = 0; r < R_; ++r) {
        float s1 = 0.f, s2 = 0.f;
        for (int ch = 0; ch < 32; ++ch) {
            size_t o = (((size_t)b * 32 + ch) * T_ + t) * R_ + r;
            s1 += p1[o]; s2 += p2[o];
        }
        kw1s[t][r] = s1; kw2s[t][r] = s2;
    }
    __syncthreads();
    float myw[R_];
    #pragma unroll
    for (int r = 0; r < R_; ++r) myw[r] = kw1s[t][r];
    float mx = -1e30f;
    for (int s = 0; s < T_; ++s) {
        float wv[12];
        const float4* qr = reinterpret_cast<const float4*>(&kw2s[s][0]);
        #pragma unroll
        for (int q = 0; q < 3; ++q) *reinterpret_cast<float4*>(&wv[q * 4]) = qr[q];
        float v = 0.f;
        #pragma unroll
        for (int r = 0; r < R_; ++r) v += myw[r] * wv[r];
        sc[t][s] = v;
        mx = fmaxf(mx, v);
    }
    float sum = 0.f;
    for (int s = 0; s < T_; ++s) {
        float e = __expf(sc[t][s] - mx);
        sc[t][s] = e;
        sum += e;
    }
    float inv = 1.0f / sum;
    __bf16* arow = att + ((size_t)b * T_ + t) * T_;
    for (int s8 = 0; s8 < T_; s8 += 8) {
        bf16x8 hv;
        #pragma unroll
        for (int q = 0; q < 8; ++q) hv[q] = (__bf16)(sc[t][s8 + q] * inv);
        *reinterpret_cast<bf16x8*>(arow + s8) = hv;
    }
}

// ---------------------------------------------------------------- kernel 3
// persistent per (b, 8-slab group): att staged once; x slabs double-buffered
// (T14 issue-early / write-late). x_bf16 is pre-swizzled so LDS copy is linear.
__global__ __launch_bounds__(256) void out_gemm_p(const __bf16* __restrict__ xb16,
                                                  const __bf16* __restrict__ att,
                                                  float* __restrict__ out) {
    __shared__ __align__(16) __bf16 attl[T_][T_];     // 32 KB swizzled
    __shared__ __align__(16) __bf16 xbuf[2][64][T_];  // 2 x 16 KB (swizzled image)
    int bid = blockIdx.x;                             // B_ * 64
    int b = bid >> 6, j = bid & 63;
    int tid = threadIdx.x;
    char* attb = (char*)&attl[0][0];

    // prologue: att (8x uint4) + slab0 (4x uint4)
    const uint4* ga = reinterpret_cast<const uint4*>(att + (size_t)b * T_ * T_);
    uint4 ar[8];
    #pragma unroll
    for (int i = 0; i < 8; ++i) ar[i] = ga[i * 256 + tid];
    const uint4* gx0 = reinterpret_cast<const uint4*>(xb16) + ((size_t)b * 512 + (size_t)j * 8) * 1024;
    uint4 xr[4];
    #pragma unroll
    for (int q = 0; q < 4; ++q) xr[q] = gx0[q * 256 + tid];
    #pragma unroll
    for (int i = 0; i < 8; ++i) {
        int e = i * 256 + tid, row = e >> 4;
        int bc = ((e & 15) * 16) ^ ((row & 7) << 4);
        *reinterpret_cast<uint4*>(attb + row * 256 + bc) = ar[i];
    }
    {
        uint4* lb = reinterpret_cast<uint4*>(&xbuf[0][0][0]);
        #pragma unroll
        for (int q = 0; q < 4; ++q) lb[q * 256 + tid] = xr[q];
    }
    __syncthreads();

    int wave = tid >> 6, lane = tid & 63;
    int r16 = lane & 15, g = lane >> 4;
    int wt = wave & 1, wn = wave >> 1;
    int swz = (r16 & 7) << 4;

    for (int i = 0; i < 8; ++i) {
        int cur = i & 1;
        uint4 nx[4];
        if (i < 7) {  // T14: issue next-slab loads early
            const uint4* gx = reinterpret_cast<const uint4*>(xb16) +
                              ((size_t)b * 512 + (size_t)j * 8 + i + 1) * 1024;
            #pragma unroll
            for (int q = 0; q < 4; ++q) nx[q] = gx[q * 256 + tid];
        }
        const char* xb = (const char*)&xbuf[cur][0][0];
        f32x4 acc[2][4] = {};
        #pragma unroll
        for (int ks = 0; ks < 4; ++ks) {
            int kc = ks * 64 + g * 16;
            bf16x8 a[4], bx[2];
            #pragma unroll
            for (int tt = 0; tt < 4; ++tt)
                a[tt] = *reinterpret_cast<const bf16x8*>(
                    attb + (wt * 64 + tt * 16 + r16) * 256 + (kc ^ swz));
            #pragma unroll
            for (int nn = 0; nn < 2; ++nn)
                bx[nn] = *reinterpret_cast<const bf16x8*>(
                    xb + (wn * 32 + nn * 16 + r16) * 256 + (kc ^ swz));
            #pragma unroll
            for (int nn = 0; nn < 2; ++nn)
                #pragma unroll
                for (int tt = 0; tt < 4; ++tt)
                    acc[nn][tt] = __builtin_amdgcn_mfma_f32_16x16x32_bf16(
                        a[tt], bx[nn], acc[nn][tt], 0, 0, 0);
        }
        int sid = j * 8 + i;
        float* o = out + (((size_t)(b * C_ + (sid >> 4))) * N_ + (sid & 15) * 64) * T_;
        #pragma unroll
        for (int nn = 0; nn < 2; ++nn) {
            int n_l = wn * 32 + nn * 16 + r16;
            #pragma unroll
            for (int tt = 0; tt < 4; ++tt)
                *reinterpret_cast<f32x4*>(o + (size_t)n_l * T_ + (wt * 64 + tt * 16 + g * 4)) = acc[nn][tt];
        }
        if (i < 7) {  // write-late into the other buffer
            uint4* lb = reinterpret_cast<uint4*>(&xbuf[cur ^ 1][0][0]);
            #pragma unroll
            for (int q = 0; q < 4; ++q) lb[q * 256 + tid] = nx[q];
        }
        __syncthreads();
    }
}

// ================================================================ LEGACY PATH (ws too small)
__global__ __launch_bounds__(256) void k_reduce_c(const float* __restrict__ x,
                                                  const float* __restrict__ alpha,
                                                  float* __restrict__ k) {
    int bid = blockIdx.x;
    int b = bid >> 7, nc = bid & 127;
    int tid = threadIdx.x;
    int nl = tid >> 5, lc = tid & 31;
    int n = nc * 8 + nl;
    const float4* xb = reinterpret_cast<const float4*>(x + ((size_t)(b * C_) * N_ + n) * T_) + lc;
    float4 acc = {0.f, 0.f, 0.f, 0.f};
    #pragma unroll 8
    for (int c = 0; c < C_; ++c) {
        float a = alpha[c];
        float4 v = xb[(size_t)c * (N_ * T_ / 4)];
        acc.x += a * v.x; acc.y += a * v.y; acc.z += a * v.z; acc.w += a * v.w;
    }
    reinterpret_cast<float4*>(k + ((size_t)b * N_ + n) * T_)[lc] = acc;
}

__global__ __launch_bounds__(128) void kw_partial(const float* __restrict__ k,
                                                  const float* __restrict__ W1,
                                                  const float* __restrict__ W2,
                                                  float* __restrict__ p1,
                                                  float* __restrict__ p2) {
    __shared__ __align__(16) float ws[NCH_][20];
    int bid = blockIdx.x;
    int b = bid >> 4, ch = bid & (CH_ - 1);
    int n0 = ch * NCH_;
    int t = threadIdx.x;
    for (int i = t; i < NCH_ * R_; i += 128) {
        int r = i / NCH_, nl = i % NCH_;
        ws[nl][r] = W1[r * N_ + n0 + nl];
        ws[nl][R_ + r] = W2[r * N_ + n0 + nl];
    }
    __syncthreads();
    float a1[R_] = {}, a2[R_] = {};
    const float* kb = k + ((size_t)b * N_ + n0) * T_ + t;
    #pragma unroll 4
    for (int nl = 0; nl < NCH_; ++nl) {
        float kv = kb[nl * T_];
        #pragma unroll
        for (int r = 0; r < R_; ++r) {
            a1[r] += kv * ws[nl][r];
            a2[r] += kv * ws[nl][R_ + r];
        }
    }
    size_t o = ((size_t)(b * CH_ + ch) * T_ + t) * R_;
    #pragma unroll
    for (int r = 0; r < R_; ++r) { p1[o + r] = a1[r]; p2[o + r] = a2[r]; }
}

__global__ __launch_bounds__(128) void scores_softmax16(const float* __restrict__ p1,
                                                        const float* __restrict__ p2,
                                                        __bf16* __restrict__ att) {
    __shared__ __align__(16) float kw1s[T_][12];
    __shared__ __align__(16) float kw2s[T_][12];
    __shared__ float sc[T_][T_ + 1];
    int b = blockIdx.x;
    int t = threadIdx.x;
    #pragma unroll
    for (int r = 0; r < R_; ++r) {
        float s1 = 0.f, s2 = 0.f;
        for (int ch = 0; ch < CH_; ++ch) {
            size_t o = ((size_t)(b * CH_ + ch) * T_ + t) * R_ + r;
            s1 += p1[o]; s2 += p2[o];
        }
        kw1s[t][r] = s1; kw2s[t][r] = s2;
    }
    __syncthreads();
    float myw[R_];
    #pragma unroll
    for (int r = 0; r < R_; ++r) myw[r] = kw1s[t][r];
    float mx = -1e30f;
    for (int s = 0; s < T_; ++s) {
        float v = 0.f;
        #pragma unroll
        for (int r = 0; r < R_; ++r) v += myw[r] * kw2s[s][r];
        sc[t][s] = v;
        mx = fmaxf(mx, v);
    }
    float sum = 0.f;
    for (int s = 0; s < T_; ++s) {
        float e = __expf(sc[t][s] - mx);
        sc[t][s] = e;
        sum += e;
    }
    float inv = 1.0f / sum;
    __bf16* arow = att + ((size_t)b * T_ + t) * T_;
    for (int s8 = 0; s8 < T_; s8 += 8) {
        bf16x8 hv;
        #pragma unroll
        for (int q = 0; q < 8; ++q) hv[q] = (__bf16)(sc[t][s8 + q] * inv);
        *reinterpret_cast<bf16x8*>(arow + s8) = hv;
    }
}

__global__ __launch_bounds__(256) void out_gemm(const float* __restrict__ x,
                                                const __bf16* __restrict__ att,
                                                float* __restrict__ out) {
    __shared__ __align__(16) __bf16 attl[T_][T_];
    __shared__ __align__(16) __bf16 xsl[64][T_];
    int bid = blockIdx.x;
    int nc = bid & 15, c = (bid >> 4) & 31, b = bid >> 9;
    int tid = threadIdx.x;
    size_t slab = ((size_t)(b * C_ + c) * N_ + nc * 64) * T_;
    char* attb = reinterpret_cast<char*>(&attl[0][0]);
    char* xb = reinterpret_cast<char*>(&xsl[0][0]);
    const uint4* ga = reinterpret_cast<const uint4*>(att + (size_t)b * T_ * T_);
    #pragma unroll
    for (int i = 0; i < 8; ++i) {
        int e = i * 256 + tid, row = e >> 4;
        int bc = ((e & 15) * 16) ^ ((row & 7) << 4);
        *reinterpret_cast<uint4*>(attb + row * 256 + bc) = ga[e];
    }
    const float4* gx = reinterpret_cast<const float4*>(x + slab);
    #pragma unroll
    for (int i = 0; i < 8; ++i) {
        int e = i * 256 + tid, row = e >> 5;
        float4 v = gx[e];
        bf16x4 hv = {(__bf16)v.x, (__bf16)v.y, (__bf16)v.z, (__bf16)v.w};
        int bc = ((e & 31) * 8) ^ ((row & 7) << 4);
        *reinterpret_cast<bf16x4*>(xb + row * 256 + bc) = hv;
    }
    __syncthreads();
    int wave = tid >> 6, lane = tid & 63;
    int r16 = lane & 15, g = lane >> 4;
    int wt = wave & 1, wn = wave >> 1;
    int swz = (r16 & 7) << 4;
    f32x4 acc[2][4] = {};
    #pragma unroll
    for (int ks = 0; ks < 4; ++ks) {
        int kc = ks * 64 + g * 16;
        bf16x8 a[4], bx[2];
        #pragma unroll
        for (int tt = 0; tt < 4; ++tt)
            a[tt] = *reinterpret_cast<const bf16x8*>(attb + (wt * 64 + tt * 16 + r16) * 256 + (kc ^ swz));
        #pragma unroll
        for (int nn = 0; nn < 2; ++nn)
            bx[nn] = *reinterpret_cast<const bf16x8*>(xb + (wn * 32 + nn * 16 + r16) * 256 + (kc ^ swz));
        #pragma unroll
        for (int nn = 0; nn < 2; ++nn)
            #pragma unroll
            for (int tt = 0; tt < 4; ++tt)
                acc[nn][tt] = __builtin_amdgcn_mfma_f32_16x16x32_bf16(a[tt], bx[nn], acc[nn][tt], 0, 0, 0);
    }
    float* o = out + slab;
    #pragma unroll
    for (int nn = 0; nn < 2; ++nn) {
        int n_l = wn * 32 + nn * 16 + r16;
        #pragma unroll
        for (int tt = 0; tt < 4; ++tt)
            *reinterpret_cast<f32x4*>(o + (size_t)n_l * T_ + (wt * 64 + tt * 16 + g * 4)) = acc[nn][tt];
    }
}

// ----------------------------------------------------------------
extern "C" void kernel_launch(void* const* d_in, const int* in_sizes, int n_in,
                              void* d_out, int out_size, void* d_ws, size_t ws_size,
                              hipStream_t stream) {
    const float* x     = (const float*)d_in[0];
    const float* W1    = (const float*)d_in[1];
    const float* W2    = (const float*)d_in[2];
    const float* alpha = (const float*)d_in[3];
    float* out = (float*)d_out;

    const size_t XB16 = 134217728;   // 16*32*1024*128*2
    const size_t PSZ  = 2621440;     // 16*32*128*10*4
    if (ws_size >= XB16 + 2 * PSZ + 524288) {
        __bf16* xb16 = (__bf16*)d_ws;
        float* p1 = (float*)((char*)d_ws + XB16);
        float* p2 = (float*)((char*)d_ws + XB16 + PSZ);
        __bf16* att = (__bf16*)((char*)d_ws + XB16 + 2 * PSZ);
        k_cast_kw<<<dim3(B_ * 32), dim3(256), 0, stream>>>(x, W1, W2, alpha, xb16, p1, p2);
        scores_softmax32<<<dim3(B_), dim3(128), 0, stream>>>(p1, p2, att);
        out_gemm_p<<<dim3(B_ * 64), dim3(256), 0, stream>>>(xb16, att, out);
    } else {
        float* k  = (float*)d_ws;
        float* p1 = k + (size_t)B_ * N_ * T_;
        float* p2 = p1 + (size_t)B_ * CH_ * T_ * R_;
        __bf16* att = (__bf16*)(p2 + (size_t)B_ * CH_ * T_ * R_);
        k_reduce_c<<<dim3(B_ * (N_ / 8)), dim3(256), 0, stream>>>(x, alpha, k);
        kw_partial<<<dim3(B_ * CH_), dim3(128), 0, stream>>>(k, W1, W2, p1, p2);
        scores_softmax16<<<dim3(B_), dim3(128), 0, stream>>>(p1, p2, att);
        out_gemm<<<dim3(B_ * C_ * (N_ / 64)), dim3(256), 0, stream>>>(x, att, out);
    }
}